// Round 13
// baseline (821.679 us; speedup 1.0000x reference)
//
#include <hip/hip_runtime.h>

#define NC 100352       // N*C = 196*512
typedef unsigned long long ull;

// ---------------------------------------------------------------------------
// QKV GEMM, shared-A: one block computes the SAME 128x64 tile of Q, K and V.
// Microtile 8 rows x 4 cols x 3 matrices (acc = 96 VGPR; the validated 8x8
// kernel with acc=64 compiled to 72 total, so this should land ~110-120,
// under the 128 allocator clamp that killed all 16x8 attempts).
// Per thread-k: 2 av + 3 bv ds_read_b128 per 96 FMAs -> LDS-issue demand
// 240 cy vs 192 VALU cy per CU-k -> VALU cap 80% (vs 67% for separate 8x8).
// Single-buffered LDS, 2 barriers/BK (validated loop shape). k-ascending
// sequential fmaf per output -> bit-identical (absmax 0.0, rounds 1-12).
// Grid 1568 = 8*196, XCD-swizzled: the 8 blocks sharing an A row-panel are
// consecutive in w -> co-reside on one XCD's L2.
// ---------------------------------------------------------------------------
__global__ __launch_bounds__(256) void gemm_qkv(
    const float* __restrict__ A,
    const float* __restrict__ W0, const float* __restrict__ W1,
    const float* __restrict__ W2,
    float* __restrict__ C0, float* __restrict__ C1, float* __restrict__ C2)
{
    __shared__ float As[16][132];     //  8,448 B
    __shared__ float Bs[3][16][68];   // 13,056 B (21.5 KB total)

    const int w = ((int)blockIdx.x & 7) * 196 + ((int)blockIdx.x >> 3);
    const int rp = w >> 3;            // row panel 0..195 (128 rows)
    const int cb = w & 7;             // col panel 0..7  (64 cols)

    const int tid = threadIdx.x;
    const int r0 = tid >> 2;          // 0..63 staging row (A: +64 too) / col (B)
    const int kq = (tid & 3) << 2;    // 0,4,8,12 staging k offset
    const int rg = (tid >> 4) << 2;   // compute row base 0..60
    const int cg = (tid & 15) << 2;   // compute col base 0..60

    const float* Ap0 = A + (size_t)(rp * 128 + r0) * 512 + kq;
    const float* Ap1 = Ap0 + (size_t)64 * 512;
    const float* Bp0 = W0 + (size_t)(cb * 64 + r0) * 512 + kq;
    const float* Bp1 = W1 + (size_t)(cb * 64 + r0) * 512 + kq;
    const float* Bp2 = W2 + (size_t)(cb * 64 + r0) * 512 + kq;

    float acc[3][8][4] = {};

    for (int k0 = 0; k0 < 512; k0 += 16) {
        const float4 a0 = *(const float4*)(Ap0 + k0);
        const float4 a1 = *(const float4*)(Ap1 + k0);
        const float4 b0 = *(const float4*)(Bp0 + k0);
        const float4 b1 = *(const float4*)(Bp1 + k0);
        const float4 b2 = *(const float4*)(Bp2 + k0);
        __syncthreads();  // previous iteration's LDS reads done
        As[kq + 0][r0] = a0.x; As[kq + 1][r0] = a0.y;
        As[kq + 2][r0] = a0.z; As[kq + 3][r0] = a0.w;
        As[kq + 0][r0 + 64] = a1.x; As[kq + 1][r0 + 64] = a1.y;
        As[kq + 2][r0 + 64] = a1.z; As[kq + 3][r0 + 64] = a1.w;
        Bs[0][kq + 0][r0] = b0.x; Bs[0][kq + 1][r0] = b0.y;
        Bs[0][kq + 2][r0] = b0.z; Bs[0][kq + 3][r0] = b0.w;
        Bs[1][kq + 0][r0] = b1.x; Bs[1][kq + 1][r0] = b1.y;
        Bs[1][kq + 2][r0] = b1.z; Bs[1][kq + 3][r0] = b1.w;
        Bs[2][kq + 0][r0] = b2.x; Bs[2][kq + 1][r0] = b2.y;
        Bs[2][kq + 2][r0] = b2.z; Bs[2][kq + 3][r0] = b2.w;
        __syncthreads();
#pragma unroll
        for (int k = 0; k < 16; ++k) {
            float av[8], bv0[4], bv1[4], bv2[4];
            *(float4*)&av[0] = *(const float4*)&As[k][rg];
            *(float4*)&av[4] = *(const float4*)&As[k][rg + 64];
            *(float4*)&bv0[0] = *(const float4*)&Bs[0][k][cg];
            *(float4*)&bv1[0] = *(const float4*)&Bs[1][k][cg];
            *(float4*)&bv2[0] = *(const float4*)&Bs[2][k][cg];
#pragma unroll
            for (int i = 0; i < 8; ++i)
#pragma unroll
                for (int j = 0; j < 4; ++j) {
                    acc[0][i][j] = fmaf(av[i], bv0[j], acc[0][i][j]);
                    acc[1][i][j] = fmaf(av[i], bv1[j], acc[1][i][j]);
                    acc[2][i][j] = fmaf(av[i], bv2[j], acc[2][i][j]);
                }
        }
    }

#pragma unroll
    for (int m = 0; m < 3; ++m) {
        float* Cb = (m == 0) ? C0 : (m == 1) ? C1 : C2;
#pragma unroll
        for (int ih = 0; ih < 2; ++ih)
#pragma unroll
            for (int i = 0; i < 4; ++i) {
                const int row = rp * 128 + rg + i + ih * 64;
                float4 o;
                o.x = acc[m][ih * 4 + i][0];
                o.y = acc[m][ih * 4 + i][1];
                o.z = acc[m][ih * 4 + i][2];
                o.w = acc[m][ih * 4 + i][3];
                *(float4*)&Cb[(size_t)row * 512 + cb * 64 + cg] = o;
            }
    }
}

// ---------------------------------------------------------------------------
// proj GEMM with bitmask A (validated round 12): 64x128 tile, 1568 blocks.
// ---------------------------------------------------------------------------
__global__ __launch_bounds__(256) void gemm_mask(
    const uint* __restrict__ Am,
    const float* __restrict__ W, const float* __restrict__ bias,
    float* __restrict__ C)
{
    __shared__ float Bs[16][132];

    const int w = ((int)blockIdx.x & 7) * 196 + ((int)blockIdx.x >> 3);
    const int rp = w >> 2;            // 0..391 (64-row panels)
    const int cb = w & 3;

    const int tid = threadIdx.x;
    const int r0 = tid >> 2;
    const int kq = (tid & 3) << 2;
    const int rg = (tid >> 4) << 2;   // 0..60 : 4 rows of 64
    const int cg = (tid & 15) << 2;   // 0..60 : cols cg / cg+64

    const float* B0 = W + (size_t)(cb * 128 + r0) * 512 + kq;
    const float* B1 = B0 + (size_t)64 * 512;

    const uint* mp[4];
#pragma unroll
    for (int i = 0; i < 4; ++i) {
        const int row = rp * 64 + rg + i;
        const int tb = row / 196;
        const int n = row - tb * 196;
        mp[i] = Am + (size_t)tb * 3136 + n * 16;
    }

    float acc[4][8] = {};

    for (int k0 = 0; k0 < 512; k0 += 16) {
        const float4 b0 = *(const float4*)(B0 + k0);
        const float4 b1 = *(const float4*)(B1 + k0);
        uint wv[4];
        const int wi = k0 >> 5;
        const int sh = k0 & 16;
#pragma unroll
        for (int m = 0; m < 4; ++m) wv[m] = mp[m][wi] >> sh;  // low 16 bits
        __syncthreads();
        Bs[kq + 0][r0] = b0.x; Bs[kq + 1][r0] = b0.y;
        Bs[kq + 2][r0] = b0.z; Bs[kq + 3][r0] = b0.w;
        Bs[kq + 0][r0 + 64] = b1.x; Bs[kq + 1][r0 + 64] = b1.y;
        Bs[kq + 2][r0 + 64] = b1.z; Bs[kq + 3][r0 + 64] = b1.w;
        __syncthreads();
#pragma unroll
        for (int k = 0; k < 16; ++k) {
            float bv[8], av[4];
            *(float4*)&bv[0] = *(const float4*)&Bs[k][cg];
            *(float4*)&bv[4] = *(const float4*)&Bs[k][cg + 64];
#pragma unroll
            for (int m = 0; m < 4; ++m)
                av[m] = ((wv[m] >> k) & 1u) ? 1.0f : 0.0f;
#pragma unroll
            for (int i = 0; i < 4; ++i)
#pragma unroll
                for (int j = 0; j < 8; ++j)
                    acc[i][j] = fmaf(av[i], bv[j], acc[i][j]);
        }
    }

#pragma unroll
    for (int i = 0; i < 4; ++i) {
        const int row = rp * 64 + rg + i;
#pragma unroll
        for (int jh = 0; jh < 2; ++jh) {
            const int col = cb * 128 + cg + jh * 64;
            float4 o;
            o.x = acc[i][jh * 4 + 0] + bias[col + 0];
            o.y = acc[i][jh * 4 + 1] + bias[col + 1];
            o.z = acc[i][jh * 4 + 2] + bias[col + 2];
            o.w = acc[i][jh * 4 + 3] + bias[col + 3];
            *(float4*)&C[(size_t)row * 512 + col] = o;
        }
    }
}

// ---------------------------------------------------------------------------
// LIF over 128 steps for Q/K/V, emitting bitmasks (4-step load MLP).
// ---------------------------------------------------------------------------
__global__ __launch_bounds__(256) void lif_mask3(
    const float* __restrict__ U0, const float* __restrict__ U1,
    const float* __restrict__ U2,
    const float* __restrict__ wq, const float* __restrict__ wk,
    const float* __restrict__ wv, ull* __restrict__ M)
{
    const int br = blockIdx.x / 392;
    const int blk = blockIdx.x - br * 392;
    const int i = blk * 256 + threadIdx.x;
    const float* U = (br == 0) ? U0 : (br == 1 ? U1 : U2);
    const float wv_ = (br == 0) ? wq[0] : (br == 1 ? wk[0] : wv[0]);
    const float sg = 1.0f / (1.0f + expf(-wv_));
    const bool l0 = (threadIdx.x & 63) == 0;
    ull* Mw = M + (size_t)br * 200704 + ((i >> 6) & 7) * 196 + (i >> 9);
    float v = 0.0f;
    for (int t0 = 0; t0 < 128; t0 += 4) {
        float x[4];
#pragma unroll
        for (int j = 0; j < 4; ++j) x[j] = U[(size_t)(t0 + j) * NC + i];
#pragma unroll
        for (int j = 0; j < 4; ++j) {
            const float h = __fadd_rn(v, __fmul_rn(__fsub_rn(x[j], v), sg));
            const bool sp = (h >= 1.0f);
            const ull m = __ballot(sp);
            if (l0) Mw[(size_t)(t0 + j) * 1568] = m;
            v = sp ? 0.0f : h;
        }
    }
}

// ---------------------------------------------------------------------------
// proj LIF: float spikes out (4-step load MLP).
// ---------------------------------------------------------------------------
__global__ __launch_bounds__(256) void lif_out(const float* __restrict__ U,
                                               const float* __restrict__ wp,
                                               float* __restrict__ out)
{
    const int i = blockIdx.x * 256 + threadIdx.x;
    const float sg = 1.0f / (1.0f + expf(-wp[0]));
    float v = 0.0f;
    for (int t0 = 0; t0 < 128; t0 += 4) {
        float x[4];
#pragma unroll
        for (int j = 0; j < 4; ++j) x[j] = U[(size_t)(t0 + j) * NC + i];
#pragma unroll
        for (int j = 0; j < 4; ++j) {
            const float h = __fadd_rn(v, __fmul_rn(__fsub_rn(x[j], v), sg));
            const bool sp = (h >= 1.0f);
            out[(size_t)(t0 + j) * NC + i] = sp ? 1.0f : 0.0f;
            v = sp ? 0.0f : h;
        }
    }
}

// ---------------------------------------------------------------------------
// Fused attention + attn_lif, 1024 THREADS (16 waves/CU; q@G rows 12-13 per
// wave instead of 24-25). Same exact integer path + _rn LIF; transpose phase
// runs on waves 0-7 (round-12 code), G/pack strided by 1024.
// Output bit-packed in proj k-order (validated rounds 10-12).
// ---------------------------------------------------------------------------
__global__ __launch_bounds__(1024) void attn_fused(const ull* __restrict__ Qm,
                                                   const ull* __restrict__ Km,
                                                   const ull* __restrict__ Vm,
                                                   const float* __restrict__ wa,
                                                   uint* __restrict__ Ym)
{
    const int b = blockIdx.x >> 3;
    const int h = blockIdx.x & 7;
    const int tid = threadIdx.x;
    const int w = tid >> 6;          // 0..15
    const int lane = tid & 63;

    __shared__ ull qrow[256], krow[256], vrow[256];
    __shared__ uint kcol32[64][4][2], vcol32[64][4][2];
    __shared__ ushort G[64][64];
    __shared__ float vstate[196][64];
    __shared__ ull sbm[208];

    const float sg = 1.0f / (1.0f + expf(-wa[0]));

    for (int t = 0; t < 4; ++t) {
        const int tb = t * 32 + b;
        const size_t mb = (size_t)tb * 1568 + (size_t)h * 196;
        if (tid < 196) {
            qrow[tid] = Qm[mb + tid];
            krow[tid] = Km[mb + tid];
            vrow[tid] = Vm[mb + tid];
        } else if (tid < 256) {
            qrow[tid] = 0; krow[tid] = 0; vrow[tid] = 0;
        }
        __syncthreads();

        if (w < 8) {  // transpose: wave w -> (j = w>>1, half = w&1)
            const int j = w >> 1, half = w & 1;
            const int base = j * 64 + half * 32;
            uint kc = 0, vc = 0;
#pragma unroll 8
            for (int m = 0; m < 32; ++m) {
                kc |= (uint)((krow[base + m] >> lane) & 1ull) << m;
                vc |= (uint)((vrow[base + m] >> lane) & 1ull) << m;
            }
            kcol32[lane][j][half] = kc; vcol32[lane][j][half] = vc;
        }
        __syncthreads();

        for (int p = tid; p < 4096; p += 1024) {
            const int d1 = p >> 6, d2 = p & 63;
            int g = 0;
#pragma unroll
            for (int j = 0; j < 4; ++j)
                g += __popc(kcol32[d1][j][0] & vcol32[d2][j][0]) +
                     __popc(kcol32[d1][j][1] & vcol32[d2][j][1]);
            G[d1][d2] = (ushort)g;
        }
        __syncthreads();

        {   // q@G + LIF: wave w owns rows [(w*196)>>4, ((w+1)*196)>>4)
            const int rbeg = (w * 196) >> 4;
            const int rend = ((w + 1) * 196) >> 4;
            int r = rbeg;
            for (; r + 1 < rend; r += 2) {
                const ull q0 = qrow[r], q1 = qrow[r + 1];
                const uint a0 = (uint)q0, a1 = (uint)(q0 >> 32);
                const uint b0 = (uint)q1, b1 = (uint)(q1 >> 32);
                uint s0 = 0, s1 = 0;
#pragma unroll
                for (int d = 0; d < 32; ++d) {
                    const uint g = G[d][lane];
                    s0 += ((a0 >> d) & 1u) * g;
                    s1 += ((b0 >> d) & 1u) * g;
                }
#pragma unroll
                for (int d = 0; d < 32; ++d) {
                    const uint g = G[32 + d][lane];
                    s0 += ((a1 >> d) & 1u) * g;
                    s1 += ((b1 >> d) & 1u) * g;
                }
                const float y0 = (float)s0 * 0.125f;
                const float v0 = t ? vstate[r][lane] : 0.0f;
                const float h0 = __fadd_rn(v0, __fmul_rn(__fsub_rn(y0, v0), sg));
                const bool sp0 = h0 >= 1.0f;
                vstate[r][lane] = sp0 ? 0.0f : h0;
                const ull m0 = __ballot(sp0);
                const float y1 = (float)s1 * 0.125f;
                const float v1 = t ? vstate[r + 1][lane] : 0.0f;
                const float h1 = __fadd_rn(v1, __fmul_rn(__fsub_rn(y1, v1), sg));
                const bool sp1 = h1 >= 1.0f;
                vstate[r + 1][lane] = sp1 ? 0.0f : h1;
                const ull m1 = __ballot(sp1);
                if (lane == 0) { sbm[r] = m0; sbm[r + 1] = m1; }
            }
            if (r < rend) {   // odd-size tail
                const ull q0 = qrow[r];
                const uint a0 = (uint)q0, a1 = (uint)(q0 >> 32);
                uint s0 = 0;
#pragma unroll
                for (int d = 0; d < 32; ++d) s0 += ((a0 >> d) & 1u) * (uint)G[d][lane];
#pragma unroll
                for (int d = 0; d < 32; ++d) s0 += ((a1 >> d) & 1u) * (uint)G[32 + d][lane];
                const float y0 = (float)s0 * 0.125f;
                const float v0 = t ? vstate[r][lane] : 0.0f;
                const float h0 = __fadd_rn(v0, __fmul_rn(__fsub_rn(y0, v0), sg));
                const bool sp0 = h0 >= 1.0f;
                vstate[r][lane] = sp0 ? 0.0f : h0;
                const ull m0 = __ballot(sp0);
                if (lane == 0) sbm[r] = m0;
            }
        }
        __syncthreads();

        // Pack spikes into proj k-order words (e changes at most once/word).
        {
            uint* Yw = Ym + (size_t)tb * 3136 + h * 392;
            for (int wd = tid; wd < 392; wd += 1024) {
                const int fb = wd * 32;
                const int e0 = fb / 196;
                const int r0 = fb - e0 * 196;
                const int run = (196 - r0 >= 32) ? 32 : (196 - r0);
                uint word = 0;
                for (int j = 0; j < run; ++j)
                    word |= (uint)((sbm[r0 + j] >> e0) & 1ull) << j;
                for (int j = run; j < 32; ++j)
                    word |= (uint)((sbm[j - run] >> (e0 + 1)) & 1ull) << j;
                Yw[wd] = word;
            }
        }
        __syncthreads();
    }
}

// ---------------------------------------------------------------------------
// Workspace (160,563,200 B):
//   u0/u1/u2 : fp32 [128][196][512] 51,380,224 B each
//   Qm/Km/Vm : [128][8][196] ull, 1,605,632 B each
//   Ym       : [128][3136] uint, 1,605,632 B
// Aliases: proj-u = u0 (dead after lif_mask3).
// ---------------------------------------------------------------------------
extern "C" void kernel_launch(void* const* d_in, const int* in_sizes, int n_in,
                              void* d_out, int out_size, void* d_ws, size_t ws_size,
                              hipStream_t stream) {
    const float* x  = (const float*)d_in[0];
    const float* Wq = (const float*)d_in[1];
    const float* Wk = (const float*)d_in[2];
    const float* Wv = (const float*)d_in[3];
    const float* Wp = (const float*)d_in[4];
    const float* bp = (const float*)d_in[5];
    const float* wq = (const float*)d_in[6];
    const float* wk = (const float*)d_in[7];
    const float* wv = (const float*)d_in[8];
    const float* wa = (const float*)d_in[9];
    const float* wp = (const float*)d_in[10];
    float* out = (float*)d_out;

    char* ws = (char*)d_ws;
    float* u0 = (float*)ws;
    float* u1 = (float*)(ws + (size_t)51380224);
    float* u2 = (float*)(ws + (size_t)2 * 51380224);
    ull* Qm   = (ull*)(ws + (size_t)3 * 51380224);
    ull* Km   = Qm + 200704;
    ull* Vm   = Km + 200704;
    uint* Ym  = (uint*)(ws + (size_t)3 * 51380224 + (size_t)3 * 1605632);
    float* up = u0;    // proj GEMM output aliases u0

    // Q/K/V GEMMs: shared-A kernel, 1568 blocks
    gemm_qkv<<<1568, 256, 0, stream>>>(x, Wq, Wk, Wv, u0, u1, u2);

    // LIF -> spike bitmasks
    lif_mask3<<<1176, 256, 0, stream>>>(u0, u1, u2, wq, wk, wv, Qm);

    // Attention + attn_lif -> packed spike words (1024 threads)
    attn_fused<<<256, 1024, 0, stream>>>(Qm, Km, Vm, wa, Ym);

    // Projection + bias from bitmask A (64x128 tiles, 1568 blocks)
    gemm_mask<<<1568, 256, 0, stream>>>(Ym, Wp, bp, up);

    // proj LIF -> output spikes
    lif_out<<<392, 256, 0, stream>>>(up, wp, out);
}